// Round 1
// baseline (1590.575 us; speedup 1.0000x reference)
//
#include <hip/hip_runtime.h>

#define SEQ   2048
#define BATCH 2
#define NH    16
#define HD    64
#define DM    1024

// ---------------------------------------------------------------------------
// GEMM1: qkv = x @ W_qkv^T + b_qkv ; scatter into q,k,v laid out [B,H,S,hd]
// M = B*S = 4096, N = 3*DM = 3072, K = DM = 1024.
// 64x64 tile, 256 threads, 4x4 microtile, K-tile 16.
// ---------------------------------------------------------------------------
__global__ __launch_bounds__(256) void qkv_gemm(const float* __restrict__ x,
                                                const float* __restrict__ W,
                                                const float* __restrict__ bias,
                                                float* __restrict__ qb,
                                                float* __restrict__ kb,
                                                float* __restrict__ vb) {
    __shared__ __align__(16) float As[16][68];  // pad 68: row stride 272B (16B-aligned), breaks bank aliasing
    __shared__ __align__(16) float Bs[16][68];
    const int t    = threadIdx.x;
    const int n0   = blockIdx.x * 64;
    const int m0   = blockIdx.y * 64;
    const int rowL = t >> 2;          // 0..63
    const int kq   = (t & 3) * 4;     // 0,4,8,12
    const int tm   = (t & 15) * 4;
    const int tn   = (t >> 4) * 4;
    float acc[4][4] = {};
    for (int k0 = 0; k0 < DM; k0 += 16) {
        const float4 a = *(const float4*)&x[(size_t)(m0 + rowL) * DM + k0 + kq];
        const float4 b = *(const float4*)&W[(size_t)(n0 + rowL) * DM + k0 + kq];
        __syncthreads();
        As[kq + 0][rowL] = a.x; As[kq + 1][rowL] = a.y;
        As[kq + 2][rowL] = a.z; As[kq + 3][rowL] = a.w;
        Bs[kq + 0][rowL] = b.x; Bs[kq + 1][rowL] = b.y;
        Bs[kq + 2][rowL] = b.z; Bs[kq + 3][rowL] = b.w;
        __syncthreads();
#pragma unroll
        for (int kk = 0; kk < 16; ++kk) {
            const float4 av = *(const float4*)&As[kk][tm];
            const float4 bv = *(const float4*)&Bs[kk][tn];
            const float ar[4] = {av.x, av.y, av.z, av.w};
            const float br[4] = {bv.x, bv.y, bv.z, bv.w};
#pragma unroll
            for (int i = 0; i < 4; ++i)
#pragma unroll
                for (int j = 0; j < 4; ++j)
                    acc[i][j] = fmaf(ar[i], br[j], acc[i][j]);
        }
    }
#pragma unroll
    for (int i = 0; i < 4; ++i) {
        const int m  = m0 + tm + i;
        const int bi = m >> 11;          // /SEQ
        const int s  = m & (SEQ - 1);
#pragma unroll
        for (int j = 0; j < 4; ++j) {
            const int n = n0 + tn + j;
            const int h = n / 192;       // 3*hd = 192 per head
            const int f = n - h * 192;
            const float val = acc[i][j] + bias[n];
            float* dst;
            int c;
            if (f < 64)       { dst = qb; c = f; }
            else if (f < 128) { dst = kb; c = f - 64; }
            else              { dst = vb; c = f - 128; }
            dst[((size_t)(bi * NH + h) * SEQ + s) * HD + c] = val;
        }
    }
}

// ---------------------------------------------------------------------------
// Flash attention fp32: one block per (b, h, 32-query tile). 256 threads.
// K/V streamed in 32-key tiles through LDS; online softmax; exp parallelized
// 8 lanes/row. mask is an additive [S,S] input (zeros in this dataset, but
// honored).
// ---------------------------------------------------------------------------
__global__ __launch_bounds__(256) void flash_attn(const float* __restrict__ qb,
                                                  const float* __restrict__ kb,
                                                  const float* __restrict__ vb,
                                                  const float* __restrict__ mask,
                                                  float* __restrict__ Ob) {
    __shared__ __align__(16) float sQ[32][65];   // pad 65: bank = (row + d) % 32
    __shared__ __align__(16) float sK[32][65];
    __shared__ __align__(16) float sV[32][68];   // pad 68: float4-readable rows
    __shared__ __align__(16) float sS[32][33];
    __shared__ float sAlpha[32], sMnew[32], sPsum[32][9];

    const int t  = threadIdx.x;
    const int qt = blockIdx.x;
    const int h  = blockIdx.y;
    const int b  = blockIdx.z;
    const int bh = b * NH + h;
    const int q0 = qt * 32;

    {   // Q tile: 32x64 = 2048 floats, 8 per thread
        const float* Qp = qb + ((size_t)bh * SEQ + q0) * HD;
        const int e = t * 8, r = e >> 6, d = e & 63;
        const float4 v0 = *(const float4*)&Qp[r * HD + d];
        const float4 v1 = *(const float4*)&Qp[r * HD + d + 4];
        sQ[r][d + 0] = v0.x; sQ[r][d + 1] = v0.y; sQ[r][d + 2] = v0.z; sQ[r][d + 3] = v0.w;
        sQ[r][d + 4] = v1.x; sQ[r][d + 5] = v1.y; sQ[r][d + 6] = v1.z; sQ[r][d + 7] = v1.w;
    }

    float m_r = -1e30f, l_r = 0.f;   // live in lanes t<32 (thread t owns row t)
    float o[8] = {};
    const int orow = t & 31;         // O row this thread accumulates
    const int oc0  = (t >> 5) * 8;   // O col group (8 cols)
    const int sr   = t >> 3;         // score row
    const int sk0  = (t & 7) * 4;    // score col start (4 entries/thread)
    const float* Kb = kb + (size_t)bh * SEQ * HD;
    const float* Vb = vb + (size_t)bh * SEQ * HD;

    for (int kt = 0; kt < SEQ / 32; ++kt) {
        const int kofs = kt * 32;
        __syncthreads();  // prev iter finished reading sK/sV/sS
        {   // K,V tiles: 8 floats each per thread
            const int e = t * 8, r = e >> 6, d = e & 63;
            const float4 k0v = *(const float4*)&Kb[(size_t)(kofs + r) * HD + d];
            const float4 k1v = *(const float4*)&Kb[(size_t)(kofs + r) * HD + d + 4];
            const float4 v0v = *(const float4*)&Vb[(size_t)(kofs + r) * HD + d];
            const float4 v1v = *(const float4*)&Vb[(size_t)(kofs + r) * HD + d + 4];
            sK[r][d + 0] = k0v.x; sK[r][d + 1] = k0v.y; sK[r][d + 2] = k0v.z; sK[r][d + 3] = k0v.w;
            sK[r][d + 4] = k1v.x; sK[r][d + 5] = k1v.y; sK[r][d + 6] = k1v.z; sK[r][d + 7] = k1v.w;
            sV[r][d + 0] = v0v.x; sV[r][d + 1] = v0v.y; sV[r][d + 2] = v0v.z; sV[r][d + 3] = v0v.w;
            sV[r][d + 4] = v1v.x; sV[r][d + 5] = v1v.y; sV[r][d + 6] = v1v.z; sV[r][d + 7] = v1v.w;
        }
        __syncthreads();
        // scores: 4 dot-64 per thread
        float sc0 = 0.f, sc1 = 0.f, sc2 = 0.f, sc3 = 0.f;
#pragma unroll
        for (int d = 0; d < HD; ++d) {
            const float qv = sQ[sr][d];
            sc0 = fmaf(qv, sK[sk0 + 0][d], sc0);
            sc1 = fmaf(qv, sK[sk0 + 1][d], sc1);
            sc2 = fmaf(qv, sK[sk0 + 2][d], sc2);
            sc3 = fmaf(qv, sK[sk0 + 3][d], sc3);
        }
        const float* mrow = mask + (size_t)(q0 + sr) * SEQ + kofs + sk0;
        sS[sr][sk0 + 0] = sc0 * 0.125f + mrow[0];
        sS[sr][sk0 + 1] = sc1 * 0.125f + mrow[1];
        sS[sr][sk0 + 2] = sc2 * 0.125f + mrow[2];
        sS[sr][sk0 + 3] = sc3 * 0.125f + mrow[3];
        __syncthreads();
        // phase A: row max + alpha (lane t == row t)
        if (t < 32) {
            float mx = sS[t][0];
#pragma unroll
            for (int i = 1; i < 32; ++i) mx = fmaxf(mx, sS[t][i]);
            const float mnew = fmaxf(m_r, mx);
            sMnew[t]  = mnew;
            sAlpha[t] = __expf(m_r - mnew);
            m_r = mnew;
        }
        __syncthreads();
        // phase B: exponentials, 8 lanes per row
        {
            const float mnew = sMnew[sr];
            float ps = 0.f;
#pragma unroll
            for (int i = 0; i < 4; ++i) {
                const float p = __expf(sS[sr][sk0 + i] - mnew);
                sS[sr][sk0 + i] = p;
                ps += p;
            }
            sPsum[sr][t & 7] = ps;
        }
        __syncthreads();
        // phase C: l update (t<32) runs concurrently with O update (all)
        if (t < 32) {
            float ssum = 0.f;
#pragma unroll
            for (int i = 0; i < 8; ++i) ssum += sPsum[t][i];
            l_r = l_r * sAlpha[t] + ssum;
        }
        const float alpha = sAlpha[orow];
#pragma unroll
        for (int j = 0; j < 8; ++j) o[j] *= alpha;
#pragma unroll
        for (int kk = 0; kk < 32; ++kk) {
            const float p   = sS[orow][kk];
            const float4 va = *(const float4*)&sV[kk][oc0];
            const float4 vb4 = *(const float4*)&sV[kk][oc0 + 4];
            o[0] = fmaf(p, va.x, o[0]);  o[1] = fmaf(p, va.y, o[1]);
            o[2] = fmaf(p, va.z, o[2]);  o[3] = fmaf(p, va.w, o[3]);
            o[4] = fmaf(p, vb4.x, o[4]); o[5] = fmaf(p, vb4.y, o[5]);
            o[6] = fmaf(p, vb4.z, o[6]); o[7] = fmaf(p, vb4.w, o[7]);
        }
    }
    __syncthreads();
    if (t < 32) sMnew[t] = 1.f / l_r;   // reuse sMnew as 1/l
    __syncthreads();
    const float inv = sMnew[orow];
    float* Op = Ob + ((size_t)bh * SEQ + q0) * HD;
#pragma unroll
    for (int j = 0; j < 8; ++j) Op[(size_t)orow * HD + oc0 + j] = o[j] * inv;
}

// ---------------------------------------------------------------------------
// GEMM2: out = values @ W_out^T + b_out, gathering A from O [B,H,S,hd].
// M = 4096, N = 1024, K = 1024.
// ---------------------------------------------------------------------------
__global__ __launch_bounds__(256) void out_gemm(const float* __restrict__ Ob,
                                                const float* __restrict__ W,
                                                const float* __restrict__ bias,
                                                float* __restrict__ out) {
    __shared__ __align__(16) float As[16][68];
    __shared__ __align__(16) float Bs[16][68];
    const int t    = threadIdx.x;
    const int n0   = blockIdx.x * 64;
    const int m0   = blockIdx.y * 64;
    const int rowL = t >> 2;
    const int kq   = (t & 3) * 4;
    const int tm   = (t & 15) * 4;
    const int tn   = (t >> 4) * 4;
    const int m    = m0 + rowL;
    const int bi   = m >> 11;
    const int s    = m & (SEQ - 1);
    float acc[4][4] = {};
    for (int k0 = 0; k0 < DM; k0 += 16) {
        const int k = k0 + kq;          // 4 consecutive k stay inside one head chunk (16 | 64)
        const int h = k >> 6, c = k & 63;
        const float4 a = *(const float4*)&Ob[((size_t)(bi * NH + h) * SEQ + s) * HD + c];
        const float4 b = *(const float4*)&W[(size_t)(n0 + rowL) * DM + k0 + kq];
        __syncthreads();
        As[kq + 0][rowL] = a.x; As[kq + 1][rowL] = a.y;
        As[kq + 2][rowL] = a.z; As[kq + 3][rowL] = a.w;
        Bs[kq + 0][rowL] = b.x; Bs[kq + 1][rowL] = b.y;
        Bs[kq + 2][rowL] = b.z; Bs[kq + 3][rowL] = b.w;
        __syncthreads();
#pragma unroll
        for (int kk = 0; kk < 16; ++kk) {
            const float4 av = *(const float4*)&As[kk][tm];
            const float4 bv = *(const float4*)&Bs[kk][tn];
            const float ar[4] = {av.x, av.y, av.z, av.w};
            const float br[4] = {bv.x, bv.y, bv.z, bv.w};
#pragma unroll
            for (int i = 0; i < 4; ++i)
#pragma unroll
                for (int j = 0; j < 4; ++j)
                    acc[i][j] = fmaf(ar[i], br[j], acc[i][j]);
        }
    }
#pragma unroll
    for (int i = 0; i < 4; ++i) {
        const int mm = m0 + tm + i;
#pragma unroll
        for (int j = 0; j < 4; ++j) {
            const int n = n0 + tn + j;
            out[(size_t)mm * DM + n] = acc[i][j] + bias[n];
        }
    }
}

// ---------------------------------------------------------------------------
extern "C" void kernel_launch(void* const* d_in, const int* in_sizes, int n_in,
                              void* d_out, int out_size, void* d_ws, size_t ws_size,
                              hipStream_t stream) {
    const float* x     = (const float*)d_in[0];
    const float* mask  = (const float*)d_in[1];
    const float* W_qkv = (const float*)d_in[2];
    const float* b_qkv = (const float*)d_in[3];
    const float* W_out = (const float*)d_in[4];
    const float* b_out = (const float*)d_in[5];
    float* out = (float*)d_out;

    const size_t NQ = (size_t)BATCH * NH * SEQ * HD;  // 4,194,304 floats (16 MB)
    float* ws = (float*)d_ws;
    float* qb = ws;
    float* kb = ws + NQ;
    float* vb = ws + 2 * NQ;
    float* Ob = ws + 3 * NQ;   // total 64 MB of d_ws

    qkv_gemm<<<dim3(3 * DM / 64, BATCH * SEQ / 64), 256, 0, stream>>>(x, W_qkv, b_qkv, qb, kb, vb);
    flash_attn<<<dim3(SEQ / 32, NH, BATCH), 256, 0, stream>>>(qb, kb, vb, mask, Ob);
    out_gemm<<<dim3(DM / 64, BATCH * SEQ / 64), 256, 0, stream>>>(Ob, W_out, b_out, out);
}

// Round 5
// 370.815 us; speedup vs baseline: 4.2894x; 4.2894x over previous
//
#include <hip/hip_runtime.h>

#define SEQ   2048
#define BATCH 2
#define NH    16
#define HD    64
#define DM    1024

typedef unsigned short u16;
typedef unsigned int   u32;
typedef __attribute__((ext_vector_type(8))) short bf8;   // 8 bf16 in 4 VGPRs
typedef __attribute__((ext_vector_type(4))) float f4;

__device__ inline u16 f2bf(float f) {                    // round-to-nearest-even
    u32 u = __builtin_bit_cast(u32, f);
    return (u16)((u + 0x7FFFu + ((u >> 16) & 1u)) >> 16);
}

__device__ inline f4 MFMA(bf8 a, bf8 b, f4 c) {
    return __builtin_amdgcn_mfma_f32_16x16x32_bf16(a, b, c, 0, 0, 0);
}

// ---------------------------------------------------------------------------
// fp32 -> bf16 cast, vectorized (float4 in, ushort4 out)
// ---------------------------------------------------------------------------
__global__ __launch_bounds__(256) void cast_bf16(const float* __restrict__ in,
                                                 u16* __restrict__ out, int n4) {
    const int i = blockIdx.x * 256 + threadIdx.x;
    if (i < n4) {
        const float4 v = ((const float4*)in)[i];
        ushort4 o;
        o.x = f2bf(v.x); o.y = f2bf(v.y); o.z = f2bf(v.z); o.w = f2bf(v.w);
        ((ushort4*)out)[i] = o;
    }
}

// ---------------------------------------------------------------------------
// bf16 MFMA GEMM: C[M,N] = A[M,K] * B[N,K]^T (+bias). 128x128 tile, 4 waves,
// each wave 64x64 via 4x4 frags of 16x16x32. BK=32, reg-staged LDS, stride 56
// (112B rows: frag reads land uniformly on banks).
// MODE 0: qkv epilogue (scatter bf16 into q/k/v [B,H,S,hd])
// MODE 1: out epilogue (fp32 [M,DM] + bias)
// ---------------------------------------------------------------------------
#define GS 56
template<int MODE>
__global__ __launch_bounds__(256) void gemm_bf16(const u16* __restrict__ A,
                                                 const u16* __restrict__ Bm,
                                                 const float* __restrict__ bias,
                                                 u16* __restrict__ q_o,
                                                 u16* __restrict__ k_o,
                                                 u16* __restrict__ v_o,
                                                 float* __restrict__ f_o) {
    __shared__ __align__(16) u16 Al[128 * GS];
    __shared__ __align__(16) u16 Bl[128 * GS];
    const int t  = threadIdx.x;
    const int l  = t & 63, w = t >> 6;
    const int n0 = blockIdx.x * 128, m0 = blockIdx.y * 128;
    const int wr = w >> 1, wc = w & 1;
    const int lr16 = l & 15, lg = l >> 4;

    const f4 zf = {0.f, 0.f, 0.f, 0.f};
    f4 acc[4][4];
#pragma unroll
    for (int m = 0; m < 4; ++m)
#pragma unroll
        for (int n = 0; n < 4; ++n) acc[m][n] = zf;

    const int rw = t >> 2;        // staging row 0..63 (and +64)
    const int kc = t & 3;         // k-chunk (8 bf16)

    for (int k0 = 0; k0 < DM; k0 += 32) {
        const float4 a0 = *(const float4*)&A[(size_t)(m0 + rw) * DM + k0 + kc * 8];
        const float4 a1 = *(const float4*)&A[(size_t)(m0 + 64 + rw) * DM + k0 + kc * 8];
        const float4 b0 = *(const float4*)&Bm[(size_t)(n0 + rw) * DM + k0 + kc * 8];
        const float4 b1 = *(const float4*)&Bm[(size_t)(n0 + 64 + rw) * DM + k0 + kc * 8];
        __syncthreads();
        *(float4*)&Al[rw * GS + kc * 8]        = a0;
        *(float4*)&Al[(64 + rw) * GS + kc * 8] = a1;
        *(float4*)&Bl[rw * GS + kc * 8]        = b0;
        *(float4*)&Bl[(64 + rw) * GS + kc * 8] = b1;
        __syncthreads();
        bf8 af[4], bfr[4];
#pragma unroll
        for (int m = 0; m < 4; ++m)
            af[m] = *(const bf8*)&Al[(wr * 64 + m * 16 + lr16) * GS + lg * 8];
#pragma unroll
        for (int n = 0; n < 4; ++n)
            bfr[n] = *(const bf8*)&Bl[(wc * 64 + n * 16 + lr16) * GS + lg * 8];
#pragma unroll
        for (int m = 0; m < 4; ++m)
#pragma unroll
            for (int n = 0; n < 4; ++n)
                acc[m][n] = MFMA(af[m], bfr[n], acc[m][n]);
    }

#pragma unroll
    for (int m = 0; m < 4; ++m)
#pragma unroll
        for (int n = 0; n < 4; ++n)
#pragma unroll
            for (int r = 0; r < 4; ++r) {
                const int M = m0 + wr * 64 + m * 16 + lg * 4 + r;
                const int N = n0 + wc * 64 + n * 16 + lr16;
                const float val = acc[m][n][r] + bias[N];
                if (MODE == 0) {
                    const int b = M >> 11, s = M & (SEQ - 1);
                    const int h = N / 192, f = N % 192;
                    const int seg = f >> 6, c = f & 63;
                    u16* dst = (seg == 0) ? q_o : ((seg == 1) ? k_o : v_o);
                    dst[(((size_t)(b * NH + h)) * SEQ + s) * HD + c] = f2bf(val);
                } else {
                    f_o[(size_t)M * DM + N] = val;
                }
            }
}

// ---------------------------------------------------------------------------
// V transpose: v [BH][S][64] -> vt [BH][64][S]  (so PV's B-operand reads are
// contiguous-key b128s). LDS-tiled 64x64, scalar b16 LDS ops, padded stride.
// ---------------------------------------------------------------------------
__global__ __launch_bounds__(256) void v_transpose(const u16* __restrict__ v,
                                                   u16* __restrict__ vt) {
    __shared__ u16 tl[64][65];
    const int t  = threadIdx.x;
    const int s0 = blockIdx.x * 64;
    const int bh = blockIdx.y;
    const u16* src = v + ((size_t)bh * SEQ + s0) * HD;
#pragma unroll
    for (int i = 0; i < 2; ++i) {
        const int c = i * 256 + t, s = c >> 3, cc = c & 7;
        const float4 d = *(const float4*)&src[s * HD + cc * 8];
        const u16* dp = (const u16*)&d;
#pragma unroll
        for (int j = 0; j < 8; ++j) tl[s][cc * 8 + j] = dp[j];
    }
    __syncthreads();
    u16* dst = vt + (size_t)bh * HD * SEQ + s0;
#pragma unroll
    for (int i = 0; i < 2; ++i) {
        const int c = i * 256 + t, dim = c >> 3, sc = c & 7;
        __align__(16) u16 tmp[8];
#pragma unroll
        for (int j = 0; j < 8; ++j) tmp[j] = tl[sc * 8 + j][dim];
        *(float4*)&dst[(size_t)dim * SEQ + sc * 8] = *(const float4*)tmp;
    }
}

// ---------------------------------------------------------------------------
// MFMA flash attention. Block = (b, h, 64 q-rows), 4 waves x 16 q-rows.
// KV tile = 64 keys staged in LDS (K row-major, V pre-transposed [dim][key]).
// Per wave per tile: 8 QK^T MFMAs -> online softmax in regs (shfl_xor over the
// 16-lane column group) -> P bf16 via wave-private LDS roundtrip -> 8 PV MFMAs.
// ---------------------------------------------------------------------------
#define KS 72
__global__ __launch_bounds__(256) void flash_attn(const u16* __restrict__ qg,
                                                  const u16* __restrict__ kg,
                                                  const u16* __restrict__ vtg,
                                                  const float* __restrict__ mask,
                                                  u16* __restrict__ og) {
    __shared__ __align__(16) u16 Kl[64 * KS];
    __shared__ __align__(16) u16 Vl[64 * KS];
    __shared__ __align__(16) u16 Pl[4 * 16 * KS];
    const int t = threadIdx.x, l = t & 63, w = t >> 6;
    const int lr16 = l & 15, lg = l >> 4;
    const int q0 = blockIdx.x * 64;
    const int h = blockIdx.y, b = blockIdx.z;
    const int bh = b * NH + h;
    const int qbase = q0 + w * 16;

    bf8 qf[2];
    {
        const u16* qp = qg + ((size_t)bh * SEQ + qbase + lr16) * HD + lg * 8;
        qf[0] = *(const bf8*)qp;
        qf[1] = *(const bf8*)(qp + 32);
    }

    const f4 zf = {0.f, 0.f, 0.f, 0.f};
    f4 Oa[4];
    float mr[4], lrow[4];
#pragma unroll
    for (int n = 0; n < 4; ++n) Oa[n] = zf;
#pragma unroll
    for (int r = 0; r < 4; ++r) { mr[r] = -1e30f; lrow[r] = 0.f; }

    const u16* Kb = kg + (size_t)bh * SEQ * HD;
    const u16* Vb = vtg + (size_t)bh * HD * SEQ;
    u16* Pw = &Pl[w * 16 * KS];

    for (int kt = 0; kt < SEQ / 64; ++kt) {
        const int kv0 = kt * 64;
        // issue global loads early (regs), overlap prev-iter compute
        float mk[4][4];
#pragma unroll
        for (int n = 0; n < 4; ++n)
#pragma unroll
            for (int r = 0; r < 4; ++r)
                mk[n][r] = mask[(size_t)(q0 + w * 16 + lg * 4 + r) * SEQ + kv0 + n * 16 + lr16];
        float4 kv[2], vv[2];
#pragma unroll
        for (int i = 0; i < 2; ++i) {
            const int c = i * 256 + t, a = c >> 3, cc = c & 7;
            kv[i] = *(const float4*)&Kb[(size_t)(kv0 + a) * HD + cc * 8];   // a = key
            vv[i] = *(const float4*)&Vb[(size_t)a * SEQ + kv0 + cc * 8];    // a = dim
        }
        __syncthreads();   // prev tile fully consumed
#pragma unroll
        for (int i = 0; i < 2; ++i) {
            const int c = i * 256 + t, a = c >> 3, cc = c & 7;
            *(float4*)&Kl[a * KS + cc * 8] = kv[i];
            *(float4*)&Vl[a * KS + cc * 8] = vv[i];
        }
        __syncthreads();
        // QK^T: scores[qrow][key], qrow=(lg*4+r), key=n*16+lr16
        f4 sc[4];
#pragma unroll
        for (int n = 0; n < 4; ++n) {
            const bf8 k0 = *(const bf8*)&Kl[(n * 16 + lr16) * KS + lg * 8];
            const bf8 k1 = *(const bf8*)&Kl[(n * 16 + lr16) * KS + 32 + lg * 8];
            f4 s = zf;
            s = MFMA(qf[0], k0, s);
            s = MFMA(qf[1], k1, s);
            sc[n] = s;
        }
#pragma unroll
        for (int n = 0; n < 4; ++n)
#pragma unroll
            for (int r = 0; r < 4; ++r)
                sc[n][r] = sc[n][r] * 0.125f + mk[n][r];
        // online softmax (row r lives in the 16 lanes sharing lg)
        float alpha[4];
#pragma unroll
        for (int r = 0; r < 4; ++r) {
            float mx = fmaxf(fmaxf(sc[0][r], sc[1][r]), fmaxf(sc[2][r], sc[3][r]));
#pragma unroll
            for (int d = 1; d < 16; d <<= 1) mx = fmaxf(mx, __shfl_xor(mx, d));
            const float mn = fmaxf(mr[r], mx);
            alpha[r] = __expf(mr[r] - mn);
            mr[r] = mn;
        }
        float rs[4] = {0.f, 0.f, 0.f, 0.f};
        u16 pb[4][4];
#pragma unroll
        for (int n = 0; n < 4; ++n)
#pragma unroll
            for (int r = 0; r < 4; ++r) {
                const float p = __expf(sc[n][r] - mr[r]);
                rs[r] += p;
                pb[n][r] = f2bf(p);
            }
#pragma unroll
        for (int r = 0; r < 4; ++r) {
            float s = rs[r];
#pragma unroll
            for (int d = 1; d < 16; d <<= 1) s += __shfl_xor(s, d);
            lrow[r] = lrow[r] * alpha[r] + s;
        }
        // P -> wave-private LDS (D-layout) -> A-frag layout
#pragma unroll
        for (int n = 0; n < 4; ++n)
#pragma unroll
            for (int r = 0; r < 4; ++r)
                Pw[(lg * 4 + r) * KS + n * 16 + lr16] = pb[n][r];
        asm volatile("s_waitcnt lgkmcnt(0)" ::: "memory");
        const bf8 pf0 = *(const bf8*)&Pw[lr16 * KS + lg * 8];
        const bf8 pf1 = *(const bf8*)&Pw[lr16 * KS + 32 + lg * 8];
        // rescale O, then PV
#pragma unroll
        for (int n = 0; n < 4; ++n)
#pragma unroll
            for (int r = 0; r < 4; ++r)
                Oa[n][r] *= alpha[r];
#pragma unroll
        for (int n = 0; n < 4; ++n) {
            const bf8 v0 = *(const bf8*)&Vl[(n * 16 + lr16) * KS + lg * 8];
            const bf8 v1 = *(const bf8*)&Vl[(n * 16 + lr16) * KS + 32 + lg * 8];
            Oa[n] = MFMA(pf0, v0, Oa[n]);
            Oa[n] = MFMA(pf1, v1, Oa[n]);
        }
    }
    float inv[4];
#pragma unroll
    for (int r = 0; r < 4; ++r) inv[r] = 1.f / lrow[r];
    // write values [b][s][h*64+dim] bf16 (row-major for out GEMM)
#pragma unroll
    for (int n = 0; n < 4; ++n)
#pragma unroll
        for (int r = 0; r < 4; ++r) {
            const int s = qbase + lg * 4 + r;
            const int dim = n * 16 + lr16;
            og[((size_t)(b * SEQ + s)) * DM + h * HD + dim] = f2bf(Oa[n][r] * inv[r]);
        }
}

// ---------------------------------------------------------------------------
extern "C" void kernel_launch(void* const* d_in, const int* in_sizes, int n_in,
                              void* d_out, int out_size, void* d_ws, size_t ws_size,
                              hipStream_t stream) {
    const float* x     = (const float*)d_in[0];
    const float* mask  = (const float*)d_in[1];
    const float* W_qkv = (const float*)d_in[2];
    const float* b_qkv = (const float*)d_in[3];
    const float* W_out = (const float*)d_in[4];
    const float* b_out = (const float*)d_in[5];
    float* out = (float*)d_out;

    const size_t NQ = (size_t)BATCH * NH * SEQ * HD;      // 4M elems
    u16* ws  = (u16*)d_ws;
    u16* xb  = ws;                                        // 4M
    u16* wqb = xb + (size_t)4096 * 1024;                  // 3M
    u16* wob = wqb + (size_t)3072 * 1024;                 // 1M
    u16* qb  = wob + (size_t)1024 * 1024;                 // 4M
    u16* kb  = qb + NQ;                                   // 4M
    u16* vb  = kb + NQ;                                   // 4M
    u16* vtb = vb + NQ;                                   // 4M
    u16* ob  = vtb + NQ;                                  // 4M  (total 56 MB)

    cast_bf16<<<4096, 256, 0, stream>>>(x, xb, 1048576);
    cast_bf16<<<3072, 256, 0, stream>>>(W_qkv, wqb, 786432);
    cast_bf16<<<1024, 256, 0, stream>>>(W_out, wob, 262144);

    gemm_bf16<0><<<dim3(24, 32), 256, 0, stream>>>(xb, wqb, b_qkv, qb, kb, vb, nullptr);
    v_transpose<<<dim3(32, 32), 256, 0, stream>>>(vb, vtb);
    flash_attn<<<dim3(SEQ / 64, NH, BATCH), 256, 0, stream>>>(qb, kb, vtb, mask, ob);
    gemm_bf16<1><<<dim3(8, 32), 256, 0, stream>>>(ob, wob, b_out, nullptr, nullptr, nullptr, out);
}

// Round 6
// 346.266 us; speedup vs baseline: 4.5935x; 1.0709x over previous
//
#include <hip/hip_runtime.h>

#define SEQ   2048
#define BATCH 2
#define NH    16
#define HD    64
#define DM    1024

typedef unsigned short u16;
typedef unsigned int   u32;
typedef __attribute__((ext_vector_type(8))) short bf8;   // 8 bf16 in 4 VGPRs
typedef __attribute__((ext_vector_type(4))) float f4;

__device__ inline u16 f2bf(float f) {                    // round-to-nearest-even
    u32 u = __builtin_bit_cast(u32, f);
    return (u16)((u + 0x7FFFu + ((u >> 16) & 1u)) >> 16);
}

__device__ inline f4 MFMA(bf8 a, bf8 b, f4 c) {
    return __builtin_amdgcn_mfma_f32_16x16x32_bf16(a, b, c, 0, 0, 0);
}

// async global->LDS, 16B per lane (m97 lever). LDS dest must be wave-uniform
// base + lane*16 (our staging mapping satisfies this by construction).
__device__ inline void gload16(const u16* g, u16* l) {
    __builtin_amdgcn_global_load_lds(
        (const __attribute__((address_space(1))) unsigned int*)(const void*)g,
        (__attribute__((address_space(3))) unsigned int*)(void*)l, 16, 0, 0);
}

// ---------------------------------------------------------------------------
// fused fp32 -> bf16 cast for x, W_qkv, W_out (one launch instead of three)
// ---------------------------------------------------------------------------
#define N4_X  1048576
#define N4_WQ 786432
#define N4_WO 262144
__global__ __launch_bounds__(256) void cast_all(const float* __restrict__ x,
                                                const float* __restrict__ wq,
                                                const float* __restrict__ wo,
                                                u16* __restrict__ xb,
                                                u16* __restrict__ wqb,
                                                u16* __restrict__ wob) {
    const int i = blockIdx.x * 256 + threadIdx.x;
    const float* src;
    u16* dst;
    int j;
    if (i < N4_X)                { src = x;  dst = xb;  j = i; }
    else if (i < N4_X + N4_WQ)   { src = wq; dst = wqb; j = i - N4_X; }
    else                         { src = wo; dst = wob; j = i - N4_X - N4_WQ; }
    const float4 v = ((const float4*)src)[j];
    ushort4 o;
    o.x = f2bf(v.x); o.y = f2bf(v.y); o.z = f2bf(v.z); o.w = f2bf(v.w);
    ((ushort4*)dst)[j] = o;
}

// ---------------------------------------------------------------------------
// bf16 MFMA GEMM, m97 structure: 128x128 tile, 4 waves, 4x4 frags 16x16x32,
// BK=32, UNPADDED [128][32] LDS filled by global_load_lds dwordx4 (lane-linear
// dest). Known ~2-4 way ds_read conflicts accepted (m97 carried 1.7e7 at 874TF).
// MODE 0: qkv epilogue (scatter bf16 into q/k/v [B,H,S,hd])
// MODE 1: out epilogue (fp32 [M,DM] + bias)
// ---------------------------------------------------------------------------
template<int MODE>
__global__ __launch_bounds__(256) void gemm_bf16(const u16* __restrict__ A,
                                                 const u16* __restrict__ Bm,
                                                 const float* __restrict__ bias,
                                                 u16* __restrict__ q_o,
                                                 u16* __restrict__ k_o,
                                                 u16* __restrict__ v_o,
                                                 float* __restrict__ f_o) {
    __shared__ __align__(16) u16 Al[128 * 32];
    __shared__ __align__(16) u16 Bl[128 * 32];
    const int t  = threadIdx.x;
    const int l  = t & 63, w = t >> 6;
    const int n0 = blockIdx.x * 128, m0 = blockIdx.y * 128;
    const int wr = w >> 1, wc = w & 1;
    const int lr16 = l & 15, lg = l >> 4;

    const f4 zf = {0.f, 0.f, 0.f, 0.f};
    f4 acc[4][4];
#pragma unroll
    for (int m = 0; m < 4; ++m)
#pragma unroll
        for (int n = 0; n < 4; ++n) acc[m][n] = zf;

    const int rw = t >> 2;        // staging row 0..63 (and +64)
    const int kc = t & 3;         // 16B k-chunk

    for (int k0 = 0; k0 < DM; k0 += 32) {
        __syncthreads();          // prev-iter frag reads complete
        gload16(&A[(size_t)(m0 + rw) * DM + k0 + kc * 8],       &Al[rw * 32 + kc * 8]);
        gload16(&A[(size_t)(m0 + 64 + rw) * DM + k0 + kc * 8],  &Al[(64 + rw) * 32 + kc * 8]);
        gload16(&Bm[(size_t)(n0 + rw) * DM + k0 + kc * 8],      &Bl[rw * 32 + kc * 8]);
        gload16(&Bm[(size_t)(n0 + 64 + rw) * DM + k0 + kc * 8], &Bl[(64 + rw) * 32 + kc * 8]);
        __syncthreads();          // compiler emits vmcnt(0) drain before barrier
        bf8 af[4], bfr[4];
#pragma unroll
        for (int m = 0; m < 4; ++m)
            af[m] = *(const bf8*)&Al[(wr * 64 + m * 16 + lr16) * 32 + lg * 8];
#pragma unroll
        for (int n = 0; n < 4; ++n)
            bfr[n] = *(const bf8*)&Bl[(wc * 64 + n * 16 + lr16) * 32 + lg * 8];
        __builtin_amdgcn_s_setprio(1);
#pragma unroll
        for (int m = 0; m < 4; ++m)
#pragma unroll
            for (int n = 0; n < 4; ++n)
                acc[m][n] = MFMA(af[m], bfr[n], acc[m][n]);
        __builtin_amdgcn_s_setprio(0);
    }

#pragma unroll
    for (int m = 0; m < 4; ++m)
#pragma unroll
        for (int n = 0; n < 4; ++n)
#pragma unroll
            for (int r = 0; r < 4; ++r) {
                const int M = m0 + wr * 64 + m * 16 + lg * 4 + r;
                const int N = n0 + wc * 64 + n * 16 + lr16;
                const float val = acc[m][n][r] + bias[N];
                if (MODE == 0) {
                    const int b = M >> 11, s = M & (SEQ - 1);
                    const int h = N / 192, f = N % 192;
                    const int seg = f >> 6, c = f & 63;
                    u16* dst = (seg == 0) ? q_o : ((seg == 1) ? k_o : v_o);
                    dst[(((size_t)(b * NH + h)) * SEQ + s) * HD + c] = f2bf(val);
                } else {
                    f_o[(size_t)M * DM + N] = val;
                }
            }
}

// ---------------------------------------------------------------------------
// V transpose: v [BH][S][64] -> vt [BH][64][S]
// ---------------------------------------------------------------------------
__global__ __launch_bounds__(256) void v_transpose(const u16* __restrict__ v,
                                                   u16* __restrict__ vt) {
    __shared__ u16 tl[64][65];
    const int t  = threadIdx.x;
    const int s0 = blockIdx.x * 64;
    const int bh = blockIdx.y;
    const u16* src = v + ((size_t)bh * SEQ + s0) * HD;
#pragma unroll
    for (int i = 0; i < 2; ++i) {
        const int c = i * 256 + t, s = c >> 3, cc = c & 7;
        const float4 d = *(const float4*)&src[s * HD + cc * 8];
        const u16* dp = (const u16*)&d;
#pragma unroll
        for (int j = 0; j < 8; ++j) tl[s][cc * 8 + j] = dp[j];
    }
    __syncthreads();
    u16* dst = vt + (size_t)bh * HD * SEQ + s0;
#pragma unroll
    for (int i = 0; i < 2; ++i) {
        const int c = i * 256 + t, dim = c >> 3, sc = c & 7;
        __align__(16) u16 tmp[8];
#pragma unroll
        for (int j = 0; j < 8; ++j) tmp[j] = tl[sc * 8 + j][dim];
        *(float4*)&dst[(size_t)dim * SEQ + sc * 8] = *(const float4*)tmp;
    }
}

// ---------------------------------------------------------------------------
// MFMA flash attention, double-buffered K/V (ONE barrier per 64-key tile),
// mask prefetched to regs one tile ahead, defer-max rescale (THR=8),
// setprio around MFMA clusters, LDS-staged coalesced epilogue.
// Block = (b, h, 64 q-rows), 4 waves x 16 q-rows.
// ---------------------------------------------------------------------------
#define KS 72
__global__ __launch_bounds__(256) void flash_attn(const u16* __restrict__ qg,
                                                  const u16* __restrict__ kg,
                                                  const u16* __restrict__ vtg,
                                                  const float* __restrict__ mask,
                                                  u16* __restrict__ og) {
    __shared__ __align__(16) u16 Kl[2][64 * KS];
    __shared__ __align__(16) u16 Vl[2][64 * KS];
    __shared__ __align__(16) u16 Pl[4 * 16 * KS];   // P roundtrip; reused as O-stage [64][KS]
    const int t = threadIdx.x, l = t & 63, w = t >> 6;
    const int lr16 = l & 15, lg = l >> 4;
    const int q0 = blockIdx.x * 64;
    const int h = blockIdx.y, b = blockIdx.z;
    const int bh = b * NH + h;
    const int qbase = q0 + w * 16;

    bf8 qf[2];
    {
        const u16* qp = qg + ((size_t)bh * SEQ + qbase + lr16) * HD + lg * 8;
        qf[0] = *(const bf8*)qp;
        qf[1] = *(const bf8*)(qp + 32);
    }

    const f4 zf = {0.f, 0.f, 0.f, 0.f};
    f4 Oa[4];
    float mr[4], lrow[4];
#pragma unroll
    for (int n = 0; n < 4; ++n) Oa[n] = zf;
#pragma unroll
    for (int r = 0; r < 4; ++r) { mr[r] = -1e30f; lrow[r] = 0.f; }

    const u16* Kb = kg + (size_t)bh * SEQ * HD;
    const u16* Vb = vtg + (size_t)bh * HD * SEQ;
    u16* Pw = &Pl[w * 16 * KS];

    float4 kvr[2], vvr[2];
    float mk[4][4], mkn[4][4];

    auto issue_kv = [&](int kv0) {
#pragma unroll
        for (int i = 0; i < 2; ++i) {
            const int c = i * 256 + t, a = c >> 3, cc = c & 7;
            kvr[i] = *(const float4*)&Kb[(size_t)(kv0 + a) * HD + cc * 8];
            vvr[i] = *(const float4*)&Vb[(size_t)a * SEQ + kv0 + cc * 8];
        }
    };
    auto write_kv = [&](int buf) {
#pragma unroll
        for (int i = 0; i < 2; ++i) {
            const int c = i * 256 + t, a = c >> 3, cc = c & 7;
            *(float4*)&Kl[buf][a * KS + cc * 8] = kvr[i];
            *(float4*)&Vl[buf][a * KS + cc * 8] = vvr[i];
        }
    };
    auto issue_mask = [&](float (&m)[4][4], int kv0) {
#pragma unroll
        for (int n = 0; n < 4; ++n)
#pragma unroll
            for (int r = 0; r < 4; ++r)
                m[n][r] = mask[(size_t)(q0 + w * 16 + lg * 4 + r) * SEQ + kv0 + n * 16 + lr16];
    };

    // prologue: tile 0 into buf0; tile 1 loads in flight
    issue_kv(0);
    issue_mask(mk, 0);
    write_kv(0);
    issue_kv(64);
    issue_mask(mkn, 64);
    __syncthreads();

    for (int kt = 0; kt < 32; ++kt) {
        const int cur = kt & 1;
        // QK^T
        f4 sc[4];
        __builtin_amdgcn_s_setprio(1);
#pragma unroll
        for (int n = 0; n < 4; ++n) {
            const bf8 k0 = *(const bf8*)&Kl[cur][(n * 16 + lr16) * KS + lg * 8];
            const bf8 k1 = *(const bf8*)&Kl[cur][(n * 16 + lr16) * KS + 32 + lg * 8];
            f4 s = zf;
            s = MFMA(qf[0], k0, s);
            s = MFMA(qf[1], k1, s);
            sc[n] = s;
        }
        __builtin_amdgcn_s_setprio(0);
#pragma unroll
        for (int n = 0; n < 4; ++n)
#pragma unroll
            for (int r = 0; r < 4; ++r)
                sc[n][r] = sc[n][r] * 0.125f + mk[n][r];
        // tile max (16-lane groups own rows)
        float pmax[4];
#pragma unroll
        for (int r = 0; r < 4; ++r) {
            float mx = fmaxf(fmaxf(sc[0][r], sc[1][r]), fmaxf(sc[2][r], sc[3][r]));
#pragma unroll
            for (int d = 1; d < 16; d <<= 1) mx = fmaxf(mx, __shfl_xor(mx, d));
            pmax[r] = mx;
        }
        // defer-max: only rescale when some row's max grew past THR=8
        bool need = false;
#pragma unroll
        for (int r = 0; r < 4; ++r) need |= (pmax[r] > mr[r] + 8.f);
        if (__any(need)) {
#pragma unroll
            for (int r = 0; r < 4; ++r) {
                const float mn = fmaxf(mr[r], pmax[r]);
                const float al = __expf(mr[r] - mn);
                mr[r] = mn;
                lrow[r] *= al;
#pragma unroll
                for (int n = 0; n < 4; ++n) Oa[n][r] *= al;
            }
        }
        float rs[4] = {0.f, 0.f, 0.f, 0.f};
        u16 pb[4][4];
#pragma unroll
        for (int n = 0; n < 4; ++n)
#pragma unroll
            for (int r = 0; r < 4; ++r) {
                const float p = __expf(sc[n][r] - mr[r]);   // bounded by e^8
                rs[r] += p;
                pb[n][r] = f2bf(p);
            }
#pragma unroll
        for (int r = 0; r < 4; ++r) {
            float s = rs[r];
#pragma unroll
            for (int d = 1; d < 16; d <<= 1) s += __shfl_xor(s, d);
            lrow[r] += s;
        }
        // P -> wave-private LDS -> A-frag layout
#pragma unroll
        for (int n = 0; n < 4; ++n)
#pragma unroll
            for (int r = 0; r < 4; ++r)
                Pw[(lg * 4 + r) * KS + n * 16 + lr16] = pb[n][r];
        asm volatile("s_waitcnt lgkmcnt(0)" ::: "memory");
        const bf8 pf0 = *(const bf8*)&Pw[lr16 * KS + lg * 8];
        const bf8 pf1 = *(const bf8*)&Pw[lr16 * KS + 32 + lg * 8];
        // PV
        __builtin_amdgcn_s_setprio(1);
#pragma unroll
        for (int n = 0; n < 4; ++n) {
            const bf8 v0 = *(const bf8*)&Vl[cur][(n * 16 + lr16) * KS + lg * 8];
            const bf8 v1 = *(const bf8*)&Vl[cur][(n * 16 + lr16) * KS + 32 + lg * 8];
            Oa[n] = MFMA(pf0, v0, Oa[n]);
            Oa[n] = MFMA(pf1, v1, Oa[n]);
        }
        __builtin_amdgcn_s_setprio(0);
        // stage tile kt+1 (loads already in flight) into buf^1; prefetch kt+2
        if (kt < 31) {
            write_kv(cur ^ 1);
#pragma unroll
            for (int n = 0; n < 4; ++n)
#pragma unroll
                for (int r = 0; r < 4; ++r) mk[n][r] = mkn[n][r];
            if (kt < 30) {
                issue_kv((kt + 2) * 64);
                issue_mask(mkn, (kt + 2) * 64);
            }
        }
        __syncthreads();
    }

    // epilogue: stage O in LDS (reuse Pl as [64][KS]) -> full-line stores
    float inv[4];
#pragma unroll
    for (int r = 0; r < 4; ++r) inv[r] = 1.f / lrow[r];
    __syncthreads();   // everyone done with Pl as P-buffer
    u16* Ol = Pl;
#pragma unroll
    for (int n = 0; n < 4; ++n)
#pragma unroll
        for (int r = 0; r < 4; ++r)
            Ol[(w * 16 + lg * 4 + r) * KS + n * 16 + lr16] = f2bf(Oa[n][r] * inv[r]);
    __syncthreads();
    {
        const int row = t >> 2, c0 = (t & 3) * 16;
        const u16* src = &Ol[row * KS + c0];
        u16* dstp = og + ((size_t)(b * SEQ + q0 + row)) * DM + h * HD + c0;
        const float4 o0 = *(const float4*)src;
        const float4 o1 = *(const float4*)(src + 8);
        *(float4*)dstp = o0;
        *(float4*)(dstp + 8) = o1;
    }
}

// ---------------------------------------------------------------------------
extern "C" void kernel_launch(void* const* d_in, const int* in_sizes, int n_in,
                              void* d_out, int out_size, void* d_ws, size_t ws_size,
                              hipStream_t stream) {
    const float* x     = (const float*)d_in[0];
    const float* mask  = (const float*)d_in[1];
    const float* W_qkv = (const float*)d_in[2];
    const float* b_qkv = (const float*)d_in[3];
    const float* W_out = (const float*)d_in[4];
    const float* b_out = (const float*)d_in[5];
    float* out = (float*)d_out;

    const size_t NQ = (size_t)BATCH * NH * SEQ * HD;      // 4M elems
    u16* ws  = (u16*)d_ws;
    u16* xb  = ws;                                        // 4M
    u16* wqb = xb + (size_t)4096 * 1024;                  // 3M
    u16* wob = wqb + (size_t)3072 * 1024;                 // 1M
    u16* qb  = wob + (size_t)1024 * 1024;                 // 4M
    u16* kb  = qb + NQ;                                   // 4M
    u16* vb  = kb + NQ;                                   // 4M
    u16* vtb = vb + NQ;                                   // 4M
    u16* ob  = vtb + NQ;                                  // 4M  (total 56 MB)

    cast_all<<<(N4_X + N4_WQ + N4_WO) / 256, 256, 0, stream>>>(x, W_qkv, W_out, xb, wqb, wob);
    gemm_bf16<0><<<dim3(24, 32), 256, 0, stream>>>(xb, wqb, b_qkv, qb, kb, vb, nullptr);
    v_transpose<<<dim3(32, 32), 256, 0, stream>>>(vb, vtb);
    flash_attn<<<dim3(SEQ / 64, NH, BATCH), 256, 0, stream>>>(qb, kb, vtb, mask, ob);
    gemm_bf16<1><<<dim3(8, 32), 256, 0, stream>>>(ob, wob, b_out, nullptr, nullptr, nullptr, out);
}